// Round 10
// baseline (110.701 us; speedup 1.0000x reference)
//
#include <hip/hip_runtime.h>
#include <hip/hip_bf16.h>
#include <hip/hip_fp16.h>

#define NB 4
#define NS 2048
#define NE 128
#define NH 16
#define ND 8

typedef __attribute__((ext_vector_type(8))) _Float16 half8;
typedef __attribute__((ext_vector_type(4))) float f32x4;

#define VSTRIDEH 1032   // shorts per vTh row (1024 + 8 pad)

__device__ __forceinline__ unsigned int pkrtz(float a, float b) {
    typedef __fp16 fp16v2 __attribute__((ext_vector_type(2)));
    union { fp16v2 h; unsigned int u; } v;
    v.h = __builtin_amdgcn_cvt_pkrtz(a, b);
    return v.u;
}
__device__ __forceinline__ unsigned short f2h(float a) {
    return __half_as_ushort(__float2half(a));   // RNE
}
__device__ __forceinline__ half8 mk_half8(unsigned u0, unsigned u1,
                                          unsigned u2, unsigned u3) {
    union { half8 h; unsigned u[4]; } v;
    v.u[0] = u0; v.u[1] = u1; v.u[2] = u2; v.u[3] = u3;
    return v.h;
}
__device__ __forceinline__ void qrow(const float* xp, const float* th, float* p) {
    float4 a = *(const float4*)xp, c = *(const float4*)(xp + 4);
    float t = 1.f;
    t *= cosf(a.x + th[0]); p[0] = t; t *= cosf(a.y + th[1]); p[1] = t;
    t *= cosf(a.z + th[2]); p[2] = t; t *= cosf(a.w + th[3]); p[3] = t;
    t *= cosf(c.x + th[4]); p[4] = t; t *= cosf(c.y + th[5]); p[5] = t;
    t *= cosf(c.z + th[6]); p[6] = t; t *= cosf(c.w + th[7]); p[7] = t;
}

// One block = one (b,h) x one eighth of query rows (256). 512 thr = 8 waves.
// TWO-PHASE flash: t is split in halves of 1024; each phase restages qt/vTh
// behind a barrier. LDS = 39 KB -> 4 blocks/CU = 8 waves/SIMD (R9 had 4:
// VALU issue util was 60%, latency-fill-bound).
//
// TRANSPOSE-FREE pipeline (verified R8/R9): S^T = mfma(A=q_t, B=q_m, C=0);
// C-layout of S^T is A-operand-shaped for PV under k-permutation
// pi(8q+j) = 4q + (j&3) + 16*(j>>2); vTh rows staged pi-reordered.
// PV A-frag = in-lane pkrtz of exp2(S^T). MASK IS FOLDED INTO vTh
// (cols scaled by km, ones-row = SC*km): masked t drop out of both
// numerator and denominator — no C-operand, no kb buffer.
// q scaled by SC = sqrt(log2e/sqrt(8)); vTh also SC-scaled and the
// ones-row is SC so O[n]/O[8] is exact. l = O column 8.
__global__ __launch_bounds__(512, 8) void attn_kernel(
        const float* __restrict__ x,
        const float* __restrict__ theta,
        const int* __restrict__ mask,
        unsigned short* __restrict__ mid) {            // f16 [B*S][NE]
    __shared__ unsigned short qt[1024 * ND + 24];      // 16,432 B (+24: A-frag overread)
    __shared__ unsigned short vTh[9 * VSTRIDEH];       // 18,576 B: pi-ordered V^T*SC*km
    __shared__ unsigned short qm[256 * ND + 8];        //  4,112 B: this block's m-rows

    const int bid = blockIdx.x;
    const int bh = bid >> 3;
    const int b = bh >> 4, h = bh & (NH - 1);
    const int meighth = bid & 7;
    const int tid = threadIdx.x;

    const float SC = 0.71421629f;   // sqrt(log2(e)/sqrt(8))

    float th[ND];
#pragma unroll
    for (int d = 0; d < ND; d++) th[d] = theta[d];

    // ---- stage qm (once): 256 m-rows, one per thread (tid<256) ----
    if (tid < 256) {
        int m = meighth * 256 + tid;
        float pm[ND];
        qrow(x + ((size_t)(b * NS + m) * NE + h * ND), th, pm);
        uint4 qa;
        qa.x = pkrtz(pm[0] * SC, pm[1] * SC);
        qa.y = pkrtz(pm[2] * SC, pm[3] * SC);
        qa.z = pkrtz(pm[4] * SC, pm[5] * SC);
        qa.w = pkrtz(pm[6] * SC, pm[7] * SC);
        *(uint4*)&qm[tid * ND] = qa;
    }
    if (tid < 24) qt[1024 * ND + tid] = 0;

    const int wave = tid >> 6, lane = tid & 63;
    const int quad = lane >> 4, l15 = lane & 15;
    const int vrow = (l15 < 9) ? l15 : 8;
    const unsigned short* vbase = &vTh[vrow * VSTRIDEH];
    half8 hz = {0, 0, 0, 0, 0, 0, 0, 0};

    // staging geometry for qt/vTh (pi-pair per thread)
    const int chs = tid >> 4, si = tid & 15;
    const int ta = 4 * (si >> 2) + 2 * (si & 1) + 16 * ((si >> 1) & 1);
    const int r0l = chs * 32 + ta;          // local t row (pair base)

    f32x4 O0 = {0.f, 0.f, 0.f, 0.f}, O1 = {0.f, 0.f, 0.f, 0.f};

    for (int p = 0; p < 2; p++) {
        if (p) __syncthreads();             // drain phase-0 readers before overwrite
        // ---- stage qt + vTh for this phase ----
        {
            int t0 = p * 1024 + r0l, t1 = t0 + 1;
            float p0[ND], p1[ND];
            qrow(x + ((size_t)(b * NS + t0) * NE + h * ND), th, p0);
            qrow(x + ((size_t)(b * NS + t1) * NE + h * ND), th, p1);
            float sk0 = mask[b * NS + t0] ? SC : 0.f;
            float sk1 = mask[b * NS + t1] ? SC : 0.f;
            uint4 qa, qb;
            qa.x = pkrtz(p0[0] * SC, p0[1] * SC);
            qa.y = pkrtz(p0[2] * SC, p0[3] * SC);
            qa.z = pkrtz(p0[4] * SC, p0[5] * SC);
            qa.w = pkrtz(p0[6] * SC, p0[7] * SC);
            qb.x = pkrtz(p1[0] * SC, p1[1] * SC);
            qb.y = pkrtz(p1[2] * SC, p1[3] * SC);
            qb.z = pkrtz(p1[4] * SC, p1[5] * SC);
            qb.w = pkrtz(p1[6] * SC, p1[7] * SC);
            *(uint4*)&qt[r0l * ND]       = qa;
            *(uint4*)&qt[(r0l + 1) * ND] = qb;
#pragma unroll
            for (int d = 0; d < ND; d++)
                *(unsigned int*)&vTh[d * VSTRIDEH + chs * 32 + 2 * si] =
                    pkrtz(p0[d] * sk0, p1[d] * sk1);
            *(unsigned int*)&vTh[8 * VSTRIDEH + chs * 32 + 2 * si] = pkrtz(sk0, sk1);
        }
        __syncthreads();

        // B operand (q_m): lane l15 = m-col; quad 0 real k, rest zero.
        half8 bm0 = quad ? hz : *(const half8*)&qm[(wave * 32 + l15) * ND];
        half8 bm1 = quad ? hz : *(const half8*)&qm[(wave * 32 + 16 + l15) * ND];

        for (int ch = 0; ch < 32; ch++) {
            int tbl = ch * 32;
            half8 at0 = *(const half8*)&qt[(tbl + l15) * ND + quad * 8];
            half8 at1 = *(const half8*)&qt[(tbl + 16 + l15) * ND + quad * 8];
            half8 vf  = *(const half8*)&vbase[tbl + quad * 8];
            f32x4 z = {0.f, 0.f, 0.f, 0.f};

            f32x4 s00 = __builtin_amdgcn_mfma_f32_16x16x32_f16(at0, bm0, z, 0, 0, 0);
            f32x4 s01 = __builtin_amdgcn_mfma_f32_16x16x32_f16(at0, bm1, z, 0, 0, 0);
            f32x4 s10 = __builtin_amdgcn_mfma_f32_16x16x32_f16(at1, bm0, z, 0, 0, 0);
            f32x4 s11 = __builtin_amdgcn_mfma_f32_16x16x32_f16(at1, bm1, z, 0, 0, 0);

            half8 pA0 = mk_half8(
                pkrtz(__builtin_amdgcn_exp2f(s00[0]), __builtin_amdgcn_exp2f(s00[1])),
                pkrtz(__builtin_amdgcn_exp2f(s00[2]), __builtin_amdgcn_exp2f(s00[3])),
                pkrtz(__builtin_amdgcn_exp2f(s10[0]), __builtin_amdgcn_exp2f(s10[1])),
                pkrtz(__builtin_amdgcn_exp2f(s10[2]), __builtin_amdgcn_exp2f(s10[3])));
            half8 pA1 = mk_half8(
                pkrtz(__builtin_amdgcn_exp2f(s01[0]), __builtin_amdgcn_exp2f(s01[1])),
                pkrtz(__builtin_amdgcn_exp2f(s01[2]), __builtin_amdgcn_exp2f(s01[3])),
                pkrtz(__builtin_amdgcn_exp2f(s11[0]), __builtin_amdgcn_exp2f(s11[1])),
                pkrtz(__builtin_amdgcn_exp2f(s11[2]), __builtin_amdgcn_exp2f(s11[3])));

            O0 = __builtin_amdgcn_mfma_f32_16x16x32_f16(pA0, vf, O0, 0, 0, 0);
            O1 = __builtin_amdgcn_mfma_f32_16x16x32_f16(pA1, vf, O1, 0, 0, 0);
        }
    }

    // ---- epilogue: l = column 8 of O; normalize; f16 store ----
    const int mbase = meighth * 256 + wave * 32;
#pragma unroll
    for (int mt = 0; mt < 2; mt++) {
        f32x4 O = mt ? O1 : O0;
#pragma unroll
        for (int r = 0; r < 4; r++) {
            float lsum = __shfl(O[r], (lane & 48) | 8, 64);
            float v = O[r] / lsum;
            if (l15 < ND) {
                int m = mbase + mt * 16 + quad * 4 + r;
                mid[(size_t)(b * NS + m) * NE + h * ND + l15] = f2h(v);
            }
        }
    }
}

// out = mid(f16) @ w^T, f16 MFMA. Block: 32 m-rows x full N=128; 4 waves.
__global__ __launch_bounds__(256) void proj_kernel(
        const unsigned short* __restrict__ mid,
        const float* __restrict__ w,
        float* __restrict__ out) {
    __shared__ unsigned short wf[NE * 136];
    __shared__ unsigned short am[32 * 136];
    const int rb = blockIdx.x * 32;
    const int tid = threadIdx.x;

    for (int i = tid; i < 2048; i += 256) {   // wf[n][k] = f16(w[n][k])
        const float* wp = w + i * 8;
        float4 a = *(const float4*)wp, c = *(const float4*)(wp + 4);
        uint4 pk;
        pk.x = pkrtz(a.x, a.y); pk.y = pkrtz(a.z, a.w);
        pk.z = pkrtz(c.x, c.y); pk.w = pkrtz(c.z, c.w);
        int n = i >> 4, k8 = (i & 15) * 8;
        *(uint4*)&wf[n * 136 + k8] = pk;
    }
    for (int i = tid; i < 512; i += 256) {    // am[r][k] = mid[rb+r][k]
        int r = i >> 4, k8 = (i & 15) * 8;
        uint4 v = *(const uint4*)&mid[(size_t)(rb + r) * NE + k8];
        *(uint4*)&am[r * 136 + k8] = v;
    }
    __syncthreads();

    const int wave = tid >> 6, lane = tid & 63;
    const int quad = lane >> 4, l15 = lane & 15;
    const int mt = wave & 1, nh = wave >> 1;

    half8 af[4];
#pragma unroll
    for (int kt = 0; kt < 4; kt++)
        af[kt] = *(const half8*)&am[(mt * 16 + l15) * 136 + kt * 32 + quad * 8];

#pragma unroll
    for (int nt = 0; nt < 4; nt++) {
        int n0 = (nh * 4 + nt) * 16;
        f32x4 acc = {0.f, 0.f, 0.f, 0.f};
#pragma unroll
        for (int kt = 0; kt < 4; kt++) {
            half8 bf = *(const half8*)&wf[(n0 + l15) * 136 + kt * 32 + quad * 8];
            acc = __builtin_amdgcn_mfma_f32_16x16x32_f16(af[kt], bf, acc, 0, 0, 0);
        }
#pragma unroll
        for (int r = 0; r < 4; r++)
            out[(size_t)(rb + mt * 16 + quad * 4 + r) * NE + n0 + l15] = acc[r];
    }
}

extern "C" void kernel_launch(void* const* d_in, const int* in_sizes, int n_in,
                              void* d_out, int out_size, void* d_ws, size_t ws_size,
                              hipStream_t stream) {
    const float* x     = (const float*)d_in[0];
    const float* theta = (const float*)d_in[1];
    const float* w_out = (const float*)d_in[2];
    const int*   mask  = (const int*)d_in[3];
    float* out = (float*)d_out;

    unsigned short* mid16 = (unsigned short*)d_ws;   // f16 [B*S][NE] = 2 MB

    attn_kernel<<<NB * NH * 8, 512, 0, stream>>>(x, theta, mask, mid16);
    proj_kernel<<<NB * NS / 32, 256, 0, stream>>>(mid16, w_out, out);
}

// Round 11
// 104.091 us; speedup vs baseline: 1.0635x; 1.0635x over previous
//
#include <hip/hip_runtime.h>
#include <hip/hip_bf16.h>
#include <hip/hip_fp16.h>

#define NB 4
#define NS 2048
#define NE 128
#define NH 16
#define ND 8

typedef __attribute__((ext_vector_type(8))) _Float16 half8;
typedef __attribute__((ext_vector_type(4))) float f32x4;

#define VSTRIDE  2056   // shorts per vT row, full-t fallback (2048 + 8 pad)
#define VSTRIDEH 1032   // shorts per vTh row, t-half partial (1024 + 8 pad)

__device__ __forceinline__ unsigned int pkrtz(float a, float b) {
    typedef __fp16 fp16v2 __attribute__((ext_vector_type(2)));
    union { fp16v2 h; unsigned int u; } v;
    v.h = __builtin_amdgcn_cvt_pkrtz(a, b);
    return v.u;
}
__device__ __forceinline__ unsigned short f2h(float a) {
    return __half_as_ushort(__float2half(a));   // RNE
}
__device__ __forceinline__ half8 mk_half8(unsigned u0, unsigned u1,
                                          unsigned u2, unsigned u3) {
    union { half8 h; unsigned u[4]; } v;
    v.u[0] = u0; v.u[1] = u1; v.u[2] = u2; v.u[3] = u3;
    return v.h;
}
__device__ __forceinline__ void qrow(const float* xp, const float* th, float* p) {
    float4 a = *(const float4*)xp, c = *(const float4*)(xp + 4);
    float t = 1.f;
    t *= cosf(a.x + th[0]); p[0] = t; t *= cosf(a.y + th[1]); p[1] = t;
    t *= cosf(a.z + th[2]); p[2] = t; t *= cosf(a.w + th[3]); p[3] = t;
    t *= cosf(c.x + th[4]); p[4] = t; t *= cosf(c.y + th[5]); p[5] = t;
    t *= cosf(c.z + th[6]); p[6] = t; t *= cosf(c.w + th[7]); p[7] = t;
}

// ---------------- PARTIAL FLASH PATH (needs ~9.4 MB ws) ----------------
// One block = (b,h) x m-eighth (256 rows) x t-HALF (1024). 512 thr = 8 waves,
// 2 m-tiles/wave, 32 chunks of 32 t. LDS 39 KB -> 4 blocks/CU = 8 waves/SIMD
// (R9 was 2 blocks/CU; fill-bound at VALUBusy 60%). Staging happens ONCE
// before the loop — no live-accumulator restage (R10's spill bug).
// Softmax needs no max-rescale (|score| bounded), so disjoint-t partials
// combine additively: block writes unnormalized O (8 f32) + l per m-row.
// Transpose-free S^T pipeline + mask folded into vTh (both verified R8-R10);
// ones-row at n=8 gives l as O column 8.
__global__ __launch_bounds__(512) void attn_partial(
        const float* __restrict__ x,
        const float* __restrict__ theta,
        const int* __restrict__ mask,
        float* __restrict__ Opart,     // [2][64][2048][8] f32
        float* __restrict__ lpart) {   // [2][64][2048]    f32
    __shared__ unsigned short qt[1024 * ND + 24];   // 16,432 B
    __shared__ unsigned short vTh[9 * VSTRIDEH];    // 18,576 B
    __shared__ unsigned short qm[256 * ND + 8];     //  4,112 B   => 39,120 B

    const int bid = blockIdx.x;
    const int half = blockIdx.y;                    // t-half
    const int bh = bid >> 3;
    const int b = bh >> 4, h = bh & (NH - 1);
    const int meighth = bid & 7;
    const int tid = threadIdx.x;

    const float SC = 0.71421629f;   // sqrt(log2(e)/sqrt(8))

    float th[ND];
#pragma unroll
    for (int d = 0; d < ND; d++) th[d] = theta[d];

    // ---- stage qm: 256 own m-rows ----
    if (tid < 256) {
        int m = meighth * 256 + tid;
        float pm[ND];
        qrow(x + ((size_t)(b * NS + m) * NE + h * ND), th, pm);
        uint4 qa;
        qa.x = pkrtz(pm[0] * SC, pm[1] * SC);
        qa.y = pkrtz(pm[2] * SC, pm[3] * SC);
        qa.z = pkrtz(pm[4] * SC, pm[5] * SC);
        qa.w = pkrtz(pm[6] * SC, pm[7] * SC);
        *(uint4*)&qm[tid * ND] = qa;
    }
    // ---- stage qt + vTh for this t-half: one pi-pair per thread ----
    {
        int chs = tid >> 4, si = tid & 15;
        int ta = 4 * (si >> 2) + 2 * (si & 1) + 16 * ((si >> 1) & 1);
        int r0l = chs * 32 + ta;
        int t0 = half * 1024 + r0l, t1 = t0 + 1;
        float p0[ND], p1[ND];
        qrow(x + ((size_t)(b * NS + t0) * NE + h * ND), th, p0);
        qrow(x + ((size_t)(b * NS + t1) * NE + h * ND), th, p1);
        float sk0 = mask[b * NS + t0] ? SC : 0.f;
        float sk1 = mask[b * NS + t1] ? SC : 0.f;
        uint4 qa, qb;
        qa.x = pkrtz(p0[0] * SC, p0[1] * SC);
        qa.y = pkrtz(p0[2] * SC, p0[3] * SC);
        qa.z = pkrtz(p0[4] * SC, p0[5] * SC);
        qa.w = pkrtz(p0[6] * SC, p0[7] * SC);
        qb.x = pkrtz(p1[0] * SC, p1[1] * SC);
        qb.y = pkrtz(p1[2] * SC, p1[3] * SC);
        qb.z = pkrtz(p1[4] * SC, p1[5] * SC);
        qb.w = pkrtz(p1[6] * SC, p1[7] * SC);
        *(uint4*)&qt[r0l * ND]       = qa;
        *(uint4*)&qt[(r0l + 1) * ND] = qb;
#pragma unroll
        for (int d = 0; d < ND; d++)
            *(unsigned int*)&vTh[d * VSTRIDEH + chs * 32 + 2 * si] =
                pkrtz(p0[d] * sk0, p1[d] * sk1);
        *(unsigned int*)&vTh[8 * VSTRIDEH + chs * 32 + 2 * si] = pkrtz(sk0, sk1);
    }
    if (tid < 24) qt[1024 * ND + tid] = 0;
    __syncthreads();

    const int wave = tid >> 6, lane = tid & 63;
    const int quad = lane >> 4, l15 = lane & 15;
    const int vrow = (l15 < 9) ? l15 : 8;
    const unsigned short* vbase = &vTh[vrow * VSTRIDEH];
    half8 hz = {0, 0, 0, 0, 0, 0, 0, 0};

    half8 bm0 = quad ? hz : *(const half8*)&qm[(wave * 32 + l15) * ND];
    half8 bm1 = quad ? hz : *(const half8*)&qm[(wave * 32 + 16 + l15) * ND];

    f32x4 O0 = {0.f, 0.f, 0.f, 0.f}, O1 = {0.f, 0.f, 0.f, 0.f};
    for (int ch = 0; ch < 32; ch++) {
        int tbl = ch * 32;
        half8 at0 = *(const half8*)&qt[(tbl + l15) * ND + quad * 8];
        half8 at1 = *(const half8*)&qt[(tbl + 16 + l15) * ND + quad * 8];
        half8 vf  = *(const half8*)&vbase[tbl + quad * 8];
        f32x4 z = {0.f, 0.f, 0.f, 0.f};

        f32x4 s00 = __builtin_amdgcn_mfma_f32_16x16x32_f16(at0, bm0, z, 0, 0, 0);
        f32x4 s01 = __builtin_amdgcn_mfma_f32_16x16x32_f16(at0, bm1, z, 0, 0, 0);
        f32x4 s10 = __builtin_amdgcn_mfma_f32_16x16x32_f16(at1, bm0, z, 0, 0, 0);
        f32x4 s11 = __builtin_amdgcn_mfma_f32_16x16x32_f16(at1, bm1, z, 0, 0, 0);

        half8 pA0 = mk_half8(
            pkrtz(__builtin_amdgcn_exp2f(s00[0]), __builtin_amdgcn_exp2f(s00[1])),
            pkrtz(__builtin_amdgcn_exp2f(s00[2]), __builtin_amdgcn_exp2f(s00[3])),
            pkrtz(__builtin_amdgcn_exp2f(s10[0]), __builtin_amdgcn_exp2f(s10[1])),
            pkrtz(__builtin_amdgcn_exp2f(s10[2]), __builtin_amdgcn_exp2f(s10[3])));
        half8 pA1 = mk_half8(
            pkrtz(__builtin_amdgcn_exp2f(s01[0]), __builtin_amdgcn_exp2f(s01[1])),
            pkrtz(__builtin_amdgcn_exp2f(s01[2]), __builtin_amdgcn_exp2f(s01[3])),
            pkrtz(__builtin_amdgcn_exp2f(s11[0]), __builtin_amdgcn_exp2f(s11[1])),
            pkrtz(__builtin_amdgcn_exp2f(s11[2]), __builtin_amdgcn_exp2f(s11[3])));

        O0 = __builtin_amdgcn_mfma_f32_16x16x32_f16(pA0, vf, O0, 0, 0, 0);
        O1 = __builtin_amdgcn_mfma_f32_16x16x32_f16(pA1, vf, O1, 0, 0, 0);
    }

    // ---- epilogue: write UNNORMALIZED partials (O cols 0..7, l = col 8) ----
    const int mbase = meighth * 256 + wave * 32;
    const size_t pb = ((size_t)half * 64 + bh) * NS;
#pragma unroll
    for (int mt = 0; mt < 2; mt++) {
        f32x4 O = mt ? O1 : O0;
#pragma unroll
        for (int r = 0; r < 4; r++) {
            int m = mbase + mt * 16 + quad * 4 + r;
            if (l15 < ND)
                Opart[(pb + m) * ND + l15] = O[r];
            else if (l15 == ND)
                lpart[pb + m] = O[r];
        }
    }
}

// proj with FUSED COMBINE: am[r][h*8+d] = (O0+O1)/(l0+l1) as f16, then
// out = am @ w^T via f16 MFMA. Block: 32 rows x N=128; 4 waves; grid 256.
__global__ __launch_bounds__(256) void proj_combine(
        const float* __restrict__ Opart,
        const float* __restrict__ lpart,
        const float* __restrict__ w,
        float* __restrict__ out) {
    __shared__ unsigned short wf[NE * 136];
    __shared__ unsigned short am[32 * 136];
    const int rb = blockIdx.x * 32;
    const int tid = threadIdx.x;

    for (int i = tid; i < 2048; i += 256) {   // wf[n][k] = f16(w[n][k])
        const float* wp = w + i * 8;
        float4 a = *(const float4*)wp, c = *(const float4*)(wp + 4);
        uint4 pk;
        pk.x = pkrtz(a.x, a.y); pk.y = pkrtz(a.z, a.w);
        pk.z = pkrtz(c.x, c.y); pk.w = pkrtz(c.z, c.w);
        int n = i >> 4, k8 = (i & 15) * 8;
        *(uint4*)&wf[n * 136 + k8] = pk;
    }
#pragma unroll
    for (int k = 0; k < 2; k++) {             // combine halves -> am (f16)
        int c = k * 256 + tid;                // 512 (row,h) cells
        int r = c >> 4, h = c & 15;
        int R = rb + r, b = R >> 11, s = R & (NS - 1);
        size_t row = ((size_t)(b * NH + h)) * NS + s;
        size_t o0 = row * ND, o1 = o0 + (size_t)64 * NS * ND;
        float4 a0 = *(const float4*)&Opart[o0];
        float4 c0 = *(const float4*)&Opart[o0 + 4];
        float4 a1 = *(const float4*)&Opart[o1];
        float4 c1 = *(const float4*)&Opart[o1 + 4];
        float l = lpart[row] + lpart[(size_t)64 * NS + row];
        float inv = 1.f / l;
        uint4 pk;
        pk.x = pkrtz((a0.x + a1.x) * inv, (a0.y + a1.y) * inv);
        pk.y = pkrtz((a0.z + a1.z) * inv, (a0.w + a1.w) * inv);
        pk.z = pkrtz((c0.x + c1.x) * inv, (c0.y + c1.y) * inv);
        pk.w = pkrtz((c0.z + c1.z) * inv, (c0.w + c1.w) * inv);
        *(uint4*)&am[r * 136 + h * 8] = pk;
    }
    __syncthreads();

    const int wave = tid >> 6, lane = tid & 63;
    const int quad = lane >> 4, l15 = lane & 15;
    const int mt = wave & 1, nh = wave >> 1;

    half8 af[4];
#pragma unroll
    for (int kt = 0; kt < 4; kt++)
        af[kt] = *(const half8*)&am[(mt * 16 + l15) * 136 + kt * 32 + quad * 8];

#pragma unroll
    for (int nt = 0; nt < 4; nt++) {
        int n0 = (nh * 4 + nt) * 16;
        f32x4 acc = {0.f, 0.f, 0.f, 0.f};
#pragma unroll
        for (int kt = 0; kt < 4; kt++) {
            half8 bf = *(const half8*)&wf[(n0 + l15) * 136 + kt * 32 + quad * 8];
            acc = __builtin_amdgcn_mfma_f32_16x16x32_f16(af[kt], bf, acc, 0, 0, 0);
        }
#pragma unroll
        for (int r = 0; r < 4; r++)
            out[(size_t)(rb + mt * 16 + quad * 4 + r) * NE + n0 + l15] = acc[r];
    }
}

// ---------------- FALLBACK PATH (R9, known-good, needs 2 MB ws) ----------------
__global__ __launch_bounds__(512) void attn_full(
        const float* __restrict__ x,
        const float* __restrict__ theta,
        const int* __restrict__ mask,
        unsigned short* __restrict__ mid) {
    __shared__ unsigned short qhl[NS * ND + 24];
    __shared__ unsigned short vT[9 * VSTRIDE];
    __shared__ float kb[NS];

    const int bid = blockIdx.x;
    const int bh = bid >> 3;
    const int b = bh >> 4, h = bh & (NH - 1);
    const int meighth = bid & 7;
    const int tid = threadIdx.x;
    const float SC = 0.71421629f;

    float th[ND];
#pragma unroll
    for (int d = 0; d < ND; d++) th[d] = theta[d];

    for (int idx = tid; idx < 1024; idx += 512) {
        int chs = idx >> 4, si = idx & 15;
        int ta = 4 * (si >> 2) + 2 * (si & 1) + 16 * ((si >> 1) & 1);
        int r0 = chs * 32 + ta, r1 = r0 + 1;
        float p0[ND], p1[ND];
        qrow(x + ((size_t)(b * NS + r0) * NE + h * ND), th, p0);
        qrow(x + ((size_t)(b * NS + r1) * NE + h * ND), th, p1);
        uint4 qa, qb;
        qa.x = pkrtz(p0[0] * SC, p0[1] * SC);
        qa.y = pkrtz(p0[2] * SC, p0[3] * SC);
        qa.z = pkrtz(p0[4] * SC, p0[5] * SC);
        qa.w = pkrtz(p0[6] * SC, p0[7] * SC);
        qb.x = pkrtz(p1[0] * SC, p1[1] * SC);
        qb.y = pkrtz(p1[2] * SC, p1[3] * SC);
        qb.z = pkrtz(p1[4] * SC, p1[5] * SC);
        qb.w = pkrtz(p1[6] * SC, p1[7] * SC);
        *(uint4*)&qhl[r0 * ND] = qa;
        *(uint4*)&qhl[r1 * ND] = qb;
#pragma unroll
        for (int d = 0; d < ND; d++)
            *(unsigned int*)&vT[d * VSTRIDE + chs * 32 + 2 * si] = pkrtz(p0[d], p1[d]);
        *(unsigned int*)&vT[8 * VSTRIDE + chs * 32 + 2 * si] = 0x3C003C00u;
    }
    for (int i = tid; i < NS; i += 512)
        kb[i] = mask[b * NS + i] ? 0.f : -30000.f;
    if (tid < 24) qhl[NS * ND + tid] = 0;
    __syncthreads();

    const int wave = tid >> 6, lane = tid & 63;
    const int quad = lane >> 4, l15 = lane & 15;
    const int mbase = meighth * 256 + wave * 32;
    half8 hz = {0, 0, 0, 0, 0, 0, 0, 0};
    half8 bm0 = quad ? hz : *(const half8*)&qhl[(mbase + l15) * ND];
    half8 bm1 = quad ? hz : *(const half8*)&qhl[(mbase + 16 + l15) * ND];
    const int vrow = (l15 < 9) ? l15 : 8;
    const unsigned short* vbase = &vT[vrow * VSTRIDE];

    f32x4 O0 = {0.f, 0.f, 0.f, 0.f}, O1 = {0.f, 0.f, 0.f, 0.f};
    for (int ch = 0; ch < 64; ch++) {
        int tb = ch * 32;
        half8 at0 = *(const half8*)&qhl[(tb + l15) * ND + quad * 8];
        half8 at1 = *(const half8*)&qhl[(tb + 16 + l15) * ND + quad * 8];
        half8 vf  = *(const half8*)&vbase[tb + quad * 8];
        f32x4 C0 = *(const f32x4*)&kb[tb + quad * 4];
        f32x4 C1 = *(const f32x4*)&kb[tb + 16 + quad * 4];
        f32x4 s00 = __builtin_amdgcn_mfma_f32_16x16x32_f16(at0, bm0, C0, 0, 0, 0);
        f32x4 s01 = __builtin_amdgcn_mfma_f32_16x16x32_f16(at0, bm1, C0, 0, 0, 0);
        f32x4 s10 = __builtin_amdgcn_mfma_f32_16x16x32_f16(at1, bm0, C1, 0, 0, 0);
        f32x4 s11 = __builtin_amdgcn_mfma_f32_16x16x32_f16(at1, bm1, C1, 0, 0, 0);
        half8 pA0 = mk_half8(
            pkrtz(__builtin_amdgcn_exp2f(s00[0]), __builtin_amdgcn_exp2f(s00[1])),
            pkrtz(__builtin_amdgcn_exp2f(s00[2]), __builtin_amdgcn_exp2f(s00[3])),
            pkrtz(__builtin_amdgcn_exp2f(s10[0]), __builtin_amdgcn_exp2f(s10[1])),
            pkrtz(__builtin_amdgcn_exp2f(s10[2]), __builtin_amdgcn_exp2f(s10[3])));
        half8 pA1 = mk_half8(
            pkrtz(__builtin_amdgcn_exp2f(s01[0]), __builtin_amdgcn_exp2f(s01[1])),
            pkrtz(__builtin_amdgcn_exp2f(s01[2]), __builtin_amdgcn_exp2f(s01[3])),
            pkrtz(__builtin_amdgcn_exp2f(s11[0]), __builtin_amdgcn_exp2f(s11[1])),
            pkrtz(__builtin_amdgcn_exp2f(s11[2]), __builtin_amdgcn_exp2f(s11[3])));
        O0 = __builtin_amdgcn_mfma_f32_16x16x32_f16(pA0, vf, O0, 0, 0, 0);
        O1 = __builtin_amdgcn_mfma_f32_16x16x32_f16(pA1, vf, O1, 0, 0, 0);
    }
#pragma unroll
    for (int mt = 0; mt < 2; mt++) {
        f32x4 O = mt ? O1 : O0;
#pragma unroll
        for (int r = 0; r < 4; r++) {
            float lsum = __shfl(O[r], (lane & 48) | 8, 64);
            float v = O[r] / lsum;
            if (l15 < ND) {
                int m = mbase + mt * 16 + quad * 4 + r;
                mid[(size_t)(b * NS + m) * NE + h * ND + l15] = f2h(v);
            }
        }
    }
}

__global__ __launch_bounds__(256) void proj_mid(
        const unsigned short* __restrict__ mid,
        const float* __restrict__ w,
        float* __restrict__ out) {
    __shared__ unsigned short wf[NE * 136];
    __shared__ unsigned short am[32 * 136];
    const int rb = blockIdx.x * 32;
    const int tid = threadIdx.x;
    for (int i = tid; i < 2048; i += 256) {
        const float* wp = w + i * 8;
        float4 a = *(const float4*)wp, c = *(const float4*)(wp + 4);
        uint4 pk;
        pk.x = pkrtz(a.x, a.y); pk.y = pkrtz(a.z, a.w);
        pk.z = pkrtz(c.x, c.y); pk.w = pkrtz(c.z, c.w);
        int n = i >> 4, k8 = (i & 15) * 8;
        *(uint4*)&wf[n * 136 + k8] = pk;
    }
    for (int i = tid; i < 512; i += 256) {
        int r = i >> 4, k8 = (i & 15) * 8;
        uint4 v = *(const uint4*)&mid[(size_t)(rb + r) * NE + k8];
        *(uint4*)&am[r * 136 + k8] = v;
    }
    __syncthreads();
    const int wave = tid >> 6, lane = tid & 63;
    const int quad = lane >> 4, l15 = lane & 15;
    const int mt = wave & 1, nh = wave >> 1;
    half8 af[4];
#pragma unroll
    for (int kt = 0; kt < 4; kt++)
        af[kt] = *(const half8*)&am[(mt * 16 + l15) * 136 + kt * 32 + quad * 8];
#pragma unroll
    for (int nt = 0; nt < 4; nt++) {
        int n0 = (nh * 4 + nt) * 16;
        f32x4 acc = {0.f, 0.f, 0.f, 0.f};
#pragma unroll
        for (int kt = 0; kt < 4; kt++) {
            half8 bf = *(const half8*)&wf[(n0 + l15) * 136 + kt * 32 + quad * 8];
            acc = __builtin_amdgcn_mfma_f32_16x16x32_f16(af[kt], bf, acc, 0, 0, 0);
        }
#pragma unroll
        for (int r = 0; r < 4; r++)
            out[(size_t)(rb + mt * 16 + quad * 4 + r) * NE + n0 + l15] = acc[r];
    }
}

extern "C" void kernel_launch(void* const* d_in, const int* in_sizes, int n_in,
                              void* d_out, int out_size, void* d_ws, size_t ws_size,
                              hipStream_t stream) {
    const float* x     = (const float*)d_in[0];
    const float* theta = (const float*)d_in[1];
    const float* w_out = (const float*)d_in[2];
    const int*   mask  = (const int*)d_in[3];
    float* out = (float*)d_out;

    const size_t opart_elems = (size_t)2 * 64 * NS * ND;   // 2.10M f32 = 8.39 MB
    const size_t lpart_elems = (size_t)2 * 64 * NS;        // 0.26M f32 = 1.05 MB
    const size_t need = (opart_elems + lpart_elems) * sizeof(float);

    if (ws_size >= need) {
        float* Opart = (float*)d_ws;
        float* lpart = Opart + opart_elems;
        attn_partial<<<dim3(NB * NH * 8, 2), 512, 0, stream>>>(x, theta, mask, Opart, lpart);
        proj_combine<<<NB * NS / 32, 256, 0, stream>>>(Opart, lpart, w_out, out);
    } else {
        unsigned short* mid16 = (unsigned short*)d_ws;     // 2 MB
        attn_full<<<NB * NH * 8, 512, 0, stream>>>(x, theta, mask, mid16);
        proj_mid<<<NB * NS / 32, 256, 0, stream>>>(mid16, w_out, out);
    }
}

// Round 12
// 103.402 us; speedup vs baseline: 1.0706x; 1.0067x over previous
//
#include <hip/hip_runtime.h>
#include <hip/hip_bf16.h>
#include <hip/hip_fp16.h>

#define NB 4
#define NS 2048
#define NE 128
#define NH 16
#define ND 8

typedef __attribute__((ext_vector_type(8))) _Float16 half8;
typedef __attribute__((ext_vector_type(4))) float f32x4;

#define VSTRIDE  2056   // shorts per vT row, full-t fallback (2048 + 8 pad)
#define VSTRIDEH 1032   // shorts per vTh row, t-half partial (1024 + 8 pad)

__device__ __forceinline__ unsigned int pkrtz(float a, float b) {
    typedef __fp16 fp16v2 __attribute__((ext_vector_type(2)));
    union { fp16v2 h; unsigned int u; } v;
    v.h = __builtin_amdgcn_cvt_pkrtz(a, b);
    return v.u;
}
__device__ __forceinline__ unsigned short f2h(float a) {
    return __half_as_ushort(__float2half(a));   // RNE
}
__device__ __forceinline__ half8 mk_half8(unsigned u0, unsigned u1,
                                          unsigned u2, unsigned u3) {
    union { half8 h; unsigned u[4]; } v;
    v.u[0] = u0; v.u[1] = u1; v.u[2] = u2; v.u[3] = u3;
    return v.h;
}
__device__ __forceinline__ void qrow(const float* xp, const float* th, float* p) {
    float4 a = *(const float4*)xp, c = *(const float4*)(xp + 4);
    float t = 1.f;
    t *= cosf(a.x + th[0]); p[0] = t; t *= cosf(a.y + th[1]); p[1] = t;
    t *= cosf(a.z + th[2]); p[2] = t; t *= cosf(a.w + th[3]); p[3] = t;
    t *= cosf(c.x + th[4]); p[4] = t; t *= cosf(c.y + th[5]); p[5] = t;
    t *= cosf(c.z + th[6]); p[6] = t; t *= cosf(c.w + th[7]); p[7] = t;
}

// ---------------- PARTIAL FLASH PATH (needs ~9.4 MB ws; proven R11) --------
// One block = (b,h) x m-QUARTER (512 rows) x t-half (1024). 512 thr = 8
// waves; each wave owns 4 m-tiles of 16 rows -> 2x the independent work per
// chunk vs R11 (8 score MFMAs, 32 exp2, 4 PV). R9->R11 showed extra WAVES
// don't convert to fill (VALUBusy stuck ~63%); the dependency chain
// (MFMA -> exp2 -> pkrtz -> MFMA) per wave is the limiter, so this round
// raises per-wave ILP instead. Chunk-wave count halves; staging per unit
// work also halves. Partials layout identical to R11 (no new ws risk).
// Transpose-free S^T pipeline + mask folded into vTh + ones-row denominator
// (all verified R8-R11).
__global__ __launch_bounds__(512) void attn_partial(
        const float* __restrict__ x,
        const float* __restrict__ theta,
        const int* __restrict__ mask,
        float* __restrict__ Opart,     // [2][64][2048][8] f32
        float* __restrict__ lpart) {   // [2][64][2048]    f32
    __shared__ unsigned short qt[1024 * ND + 24];   // 16,432 B
    __shared__ unsigned short vTh[9 * VSTRIDEH];    // 18,576 B
    __shared__ unsigned short qm[512 * ND + 8];     //  8,208 B   => 43,216 B

    const int bid = blockIdx.x;                     // 0..255
    const int half = blockIdx.y;                    // t-half
    const int bh = bid >> 2;
    const int b = bh >> 4, h = bh & (NH - 1);
    const int mquart = bid & 3;
    const int tid = threadIdx.x;

    const float SC = 0.71421629f;   // sqrt(log2(e)/sqrt(8))

    float th[ND];
#pragma unroll
    for (int d = 0; d < ND; d++) th[d] = theta[d];

    // ---- stage qm: 512 own m-rows, one per thread ----
    {
        int m = mquart * 512 + tid;
        float pm[ND];
        qrow(x + ((size_t)(b * NS + m) * NE + h * ND), th, pm);
        uint4 qa;
        qa.x = pkrtz(pm[0] * SC, pm[1] * SC);
        qa.y = pkrtz(pm[2] * SC, pm[3] * SC);
        qa.z = pkrtz(pm[4] * SC, pm[5] * SC);
        qa.w = pkrtz(pm[6] * SC, pm[7] * SC);
        *(uint4*)&qm[tid * ND] = qa;
    }
    // ---- stage qt + vTh for this t-half: one pi-pair per thread ----
    {
        int chs = tid >> 4, si = tid & 15;
        int ta = 4 * (si >> 2) + 2 * (si & 1) + 16 * ((si >> 1) & 1);
        int r0l = chs * 32 + ta;
        int t0 = half * 1024 + r0l, t1 = t0 + 1;
        float p0[ND], p1[ND];
        qrow(x + ((size_t)(b * NS + t0) * NE + h * ND), th, p0);
        qrow(x + ((size_t)(b * NS + t1) * NE + h * ND), th, p1);
        float sk0 = mask[b * NS + t0] ? SC : 0.f;
        float sk1 = mask[b * NS + t1] ? SC : 0.f;
        uint4 qa, qb;
        qa.x = pkrtz(p0[0] * SC, p0[1] * SC);
        qa.y = pkrtz(p0[2] * SC, p0[3] * SC);
        qa.z = pkrtz(p0[4] * SC, p0[5] * SC);
        qa.w = pkrtz(p0[6] * SC, p0[7] * SC);
        qb.x = pkrtz(p1[0] * SC, p1[1] * SC);
        qb.y = pkrtz(p1[2] * SC, p1[3] * SC);
        qb.z = pkrtz(p1[4] * SC, p1[5] * SC);
        qb.w = pkrtz(p1[6] * SC, p1[7] * SC);
        *(uint4*)&qt[r0l * ND]       = qa;
        *(uint4*)&qt[(r0l + 1) * ND] = qb;
#pragma unroll
        for (int d = 0; d < ND; d++)
            *(unsigned int*)&vTh[d * VSTRIDEH + chs * 32 + 2 * si] =
                pkrtz(p0[d] * sk0, p1[d] * sk1);
        *(unsigned int*)&vTh[8 * VSTRIDEH + chs * 32 + 2 * si] = pkrtz(sk0, sk1);
    }
    if (tid < 24) qt[1024 * ND + tid] = 0;
    __syncthreads();

    const int wave = tid >> 6, lane = tid & 63;
    const int quad = lane >> 4, l15 = lane & 15;
    const int vrow = (l15 < 9) ? l15 : 8;
    const unsigned short* vbase = &vTh[vrow * VSTRIDEH];
    half8 hz = {0, 0, 0, 0, 0, 0, 0, 0};

    // B operands: 4 m-tiles per wave (64 m-rows)
    half8 bm[4];
#pragma unroll
    for (int mt = 0; mt < 4; mt++)
        bm[mt] = quad ? hz : *(const half8*)&qm[(wave * 64 + mt * 16 + l15) * ND];

    f32x4 O[4] = {{0.f,0.f,0.f,0.f},{0.f,0.f,0.f,0.f},
                  {0.f,0.f,0.f,0.f},{0.f,0.f,0.f,0.f}};
    for (int ch = 0; ch < 32; ch++) {
        int tbl = ch * 32;
        half8 at0 = *(const half8*)&qt[(tbl + l15) * ND + quad * 8];
        half8 at1 = *(const half8*)&qt[(tbl + 16 + l15) * ND + quad * 8];
        half8 vf  = *(const half8*)&vbase[tbl + quad * 8];
        f32x4 z = {0.f, 0.f, 0.f, 0.f};

#pragma unroll
        for (int mt = 0; mt < 4; mt++) {
            f32x4 sa = __builtin_amdgcn_mfma_f32_16x16x32_f16(at0, bm[mt], z, 0, 0, 0);
            f32x4 sb = __builtin_amdgcn_mfma_f32_16x16x32_f16(at1, bm[mt], z, 0, 0, 0);
            half8 pA = mk_half8(
                pkrtz(__builtin_amdgcn_exp2f(sa[0]), __builtin_amdgcn_exp2f(sa[1])),
                pkrtz(__builtin_amdgcn_exp2f(sa[2]), __builtin_amdgcn_exp2f(sa[3])),
                pkrtz(__builtin_amdgcn_exp2f(sb[0]), __builtin_amdgcn_exp2f(sb[1])),
                pkrtz(__builtin_amdgcn_exp2f(sb[2]), __builtin_amdgcn_exp2f(sb[3])));
            O[mt] = __builtin_amdgcn_mfma_f32_16x16x32_f16(pA, vf, O[mt], 0, 0, 0);
        }
    }

    // ---- epilogue: write UNNORMALIZED partials (O cols 0..7, l = col 8) ----
    const int mbase = mquart * 512 + wave * 64;
    const size_t pb = ((size_t)half * 64 + bh) * NS;
#pragma unroll
    for (int mt = 0; mt < 4; mt++) {
#pragma unroll
        for (int r = 0; r < 4; r++) {
            int m = mbase + mt * 16 + quad * 4 + r;
            if (l15 < ND)
                Opart[(pb + m) * ND + l15] = O[mt][r];
            else if (l15 == ND)
                lpart[pb + m] = O[mt][r];
        }
    }
}

// proj with FUSED COMBINE: am[r][h*8+d] = (O0+O1)/(l0+l1) as f16, then
// out = am @ w^T via f16 MFMA. Block: 32 rows x N=128; 4 waves; grid 256.
__global__ __launch_bounds__(256) void proj_combine(
        const float* __restrict__ Opart,
        const float* __restrict__ lpart,
        const float* __restrict__ w,
        float* __restrict__ out) {
    __shared__ unsigned short wf[NE * 136];
    __shared__ unsigned short am[32 * 136];
    const int rb = blockIdx.x * 32;
    const int tid = threadIdx.x;

    for (int i = tid; i < 2048; i += 256) {   // wf[n][k] = f16(w[n][k])
        const float* wp = w + i * 8;
        float4 a = *(const float4*)wp, c = *(const float4*)(wp + 4);
        uint4 pk;
        pk.x = pkrtz(a.x, a.y); pk.y = pkrtz(a.z, a.w);
        pk.z = pkrtz(c.x, c.y); pk.w = pkrtz(c.z, c.w);
        int n = i >> 4, k8 = (i & 15) * 8;
        *(uint4*)&wf[n * 136 + k8] = pk;
    }
#pragma unroll
    for (int k = 0; k < 2; k++) {             // combine halves -> am (f16)
        int c = k * 256 + tid;                // 512 (row,h) cells
        int r = c >> 4, h = c & 15;
        int R = rb + r, b = R >> 11, s = R & (NS - 1);
        size_t row = ((size_t)(b * NH + h)) * NS + s;
        size_t o0 = row * ND, o1 = o0 + (size_t)64 * NS * ND;
        float4 a0 = *(const float4*)&Opart[o0];
        float4 c0 = *(const float4*)&Opart[o0 + 4];
        float4 a1 = *(const float4*)&Opart[o1];
        float4 c1 = *(const float4*)&Opart[o1 + 4];
        float l = lpart[row] + lpart[(size_t)64 * NS + row];
        float inv = 1.f / l;
        uint4 pk;
        pk.x = pkrtz((a0.x + a1.x) * inv, (a0.y + a1.y) * inv);
        pk.y = pkrtz((a0.z + a1.z) * inv, (a0.w + a1.w) * inv);
        pk.z = pkrtz((c0.x + c1.x) * inv, (c0.y + c1.y) * inv);
        pk.w = pkrtz((c0.z + c1.z) * inv, (c0.w + c1.w) * inv);
        *(uint4*)&am[r * 136 + h * 8] = pk;
    }
    __syncthreads();

    const int wave = tid >> 6, lane = tid & 63;
    const int quad = lane >> 4, l15 = lane & 15;
    const int mt = wave & 1, nh = wave >> 1;

    half8 af[4];
#pragma unroll
    for (int kt = 0; kt < 4; kt++)
        af[kt] = *(const half8*)&am[(mt * 16 + l15) * 136 + kt * 32 + quad * 8];

#pragma unroll
    for (int nt = 0; nt < 4; nt++) {
        int n0 = (nh * 4 + nt) * 16;
        f32x4 acc = {0.f, 0.f, 0.f, 0.f};
#pragma unroll
        for (int kt = 0; kt < 4; kt++) {
            half8 bf = *(const half8*)&wf[(n0 + l15) * 136 + kt * 32 + quad * 8];
            acc = __builtin_amdgcn_mfma_f32_16x16x32_f16(af[kt], bf, acc, 0, 0, 0);
        }
#pragma unroll
        for (int r = 0; r < 4; r++)
            out[(size_t)(rb + mt * 16 + quad * 4 + r) * NE + n0 + l15] = acc[r];
    }
}

// ---------------- FALLBACK PATH (R9, known-good, needs 2 MB ws) ----------------
__global__ __launch_bounds__(512) void attn_full(
        const float* __restrict__ x,
        const float* __restrict__ theta,
        const int* __restrict__ mask,
        unsigned short* __restrict__ mid) {
    __shared__ unsigned short qhl[NS * ND + 24];
    __shared__ unsigned short vT[9 * VSTRIDE];
    __shared__ float kb[NS];

    const int bid = blockIdx.x;
    const int bh = bid >> 3;
    const int b = bh >> 4, h = bh & (NH - 1);
    const int meighth = bid & 7;
    const int tid = threadIdx.x;
    const float SC = 0.71421629f;

    float th[ND];
#pragma unroll
    for (int d = 0; d < ND; d++) th[d] = theta[d];

    for (int idx = tid; idx < 1024; idx += 512) {
        int chs = idx >> 4, si = idx & 15;
        int ta = 4 * (si >> 2) + 2 * (si & 1) + 16 * ((si >> 1) & 1);
        int r0 = chs * 32 + ta, r1 = r0 + 1;
        float p0[ND], p1[ND];
        qrow(x + ((size_t)(b * NS + r0) * NE + h * ND), th, p0);
        qrow(x + ((size_t)(b * NS + r1) * NE + h * ND), th, p1);
        uint4 qa, qb;
        qa.x = pkrtz(p0[0] * SC, p0[1] * SC);
        qa.y = pkrtz(p0[2] * SC, p0[3] * SC);
        qa.z = pkrtz(p0[4] * SC, p0[5] * SC);
        qa.w = pkrtz(p0[6] * SC, p0[7] * SC);
        qb.x = pkrtz(p1[0] * SC, p1[1] * SC);
        qb.y = pkrtz(p1[2] * SC, p1[3] * SC);
        qb.z = pkrtz(p1[4] * SC, p1[5] * SC);
        qb.w = pkrtz(p1[6] * SC, p1[7] * SC);
        *(uint4*)&qhl[r0 * ND] = qa;
        *(uint4*)&qhl[r1 * ND] = qb;
#pragma unroll
        for (int d = 0; d < ND; d++)
            *(unsigned int*)&vT[d * VSTRIDE + chs * 32 + 2 * si] = pkrtz(p0[d], p1[d]);
        *(unsigned int*)&vT[8 * VSTRIDE + chs * 32 + 2 * si] = 0x3C003C00u;
    }
    for (int i = tid; i < NS; i += 512)
        kb[i] = mask[b * NS + i] ? 0.f : -30000.f;
    if (tid < 24) qhl[NS * ND + tid] = 0;
    __syncthreads();

    const int wave = tid >> 6, lane = tid & 63;
    const int quad = lane >> 4, l15 = lane & 15;
    const int mbase = meighth * 256 + wave * 32;
    half8 hz = {0, 0, 0, 0, 0, 0, 0, 0};
    half8 bm0 = quad ? hz : *(const half8*)&qhl[(mbase + l15) * ND];
    half8 bm1 = quad ? hz : *(const half8*)&qhl[(mbase + 16 + l15) * ND];
    const int vrow = (l15 < 9) ? l15 : 8;
    const unsigned short* vbase = &vT[vrow * VSTRIDE];

    f32x4 O0 = {0.f, 0.f, 0.f, 0.f}, O1 = {0.f, 0.f, 0.f, 0.f};
    for (int ch = 0; ch < 64; ch++) {
        int tb = ch * 32;
        half8 at0 = *(const half8*)&qhl[(tb + l15) * ND + quad * 8];
        half8 at1 = *(const half8*)&qhl[(tb + 16 + l15) * ND + quad * 8];
        half8 vf  = *(const half8*)&vbase[tb + quad * 8];
        f32x4 C0 = *(const f32x4*)&kb[tb + quad * 4];
        f32x4 C1 = *(const f32x4*)&kb[tb + 16 + quad * 4];
        f32x4 s00 = __builtin_amdgcn_mfma_f32_16x16x32_f16(at0, bm0, C0, 0, 0, 0);
        f32x4 s01 = __builtin_amdgcn_mfma_f32_16x16x32_f16(at0, bm1, C0, 0, 0, 0);
        f32x4 s10 = __builtin_amdgcn_mfma_f32_16x16x32_f16(at1, bm0, C1, 0, 0, 0);
        f32x4 s11 = __builtin_amdgcn_mfma_f32_16x16x32_f16(at1, bm1, C1, 0, 0, 0);
        half8 pA0 = mk_half8(
            pkrtz(__builtin_amdgcn_exp2f(s00[0]), __builtin_amdgcn_exp2f(s00[1])),
            pkrtz(__builtin_amdgcn_exp2f(s00[2]), __builtin_amdgcn_exp2f(s00[3])),
            pkrtz(__builtin_amdgcn_exp2f(s10[0]), __builtin_amdgcn_exp2f(s10[1])),
            pkrtz(__builtin_amdgcn_exp2f(s10[2]), __builtin_amdgcn_exp2f(s10[3])));
        half8 pA1 = mk_half8(
            pkrtz(__builtin_amdgcn_exp2f(s01[0]), __builtin_amdgcn_exp2f(s01[1])),
            pkrtz(__builtin_amdgcn_exp2f(s01[2]), __builtin_amdgcn_exp2f(s01[3])),
            pkrtz(__builtin_amdgcn_exp2f(s11[0]), __builtin_amdgcn_exp2f(s11[1])),
            pkrtz(__builtin_amdgcn_exp2f(s11[2]), __builtin_amdgcn_exp2f(s11[3])));
        O0 = __builtin_amdgcn_mfma_f32_16x16x32_f16(pA0, vf, O0, 0, 0, 0);
        O1 = __builtin_amdgcn_mfma_f32_16x16x32_f16(pA1, vf, O1, 0, 0, 0);
    }
#pragma unroll
    for (int mt = 0; mt < 2; mt++) {
        f32x4 O = mt ? O1 : O0;
#pragma unroll
        for (int r = 0; r < 4; r++) {
            float lsum = __shfl(O[r], (lane & 48) | 8, 64);
            float v = O[r] / lsum;
            if (l15 < ND) {
                int m = mbase + mt * 16 + quad * 4 + r;
                mid[(size_t)(b * NS + m) * NE + h * ND + l15] = f2h(v);
            }
        }
    }
}

__global__ __launch_bounds__(256) void proj_mid(
        const unsigned short* __restrict__ mid,
        const float* __restrict__ w,
        float* __restrict__ out) {
    __shared__ unsigned short wf[NE * 136];
    __shared__ unsigned short am[32 * 136];
    const int rb = blockIdx.x * 32;
    const int tid = threadIdx.x;
    for (int i = tid; i < 2048; i += 256) {
        const float* wp = w + i * 8;
        float4 a = *(const float4*)wp, c = *(const float4*)(wp + 4);
        uint4 pk;
        pk.x = pkrtz(a.x, a.y); pk.y = pkrtz(a.z, a.w);
        pk.z = pkrtz(c.x, c.y); pk.w = pkrtz(c.z, c.w);
        int n = i >> 4, k8 = (i & 15) * 8;
        *(uint4*)&wf[n * 136 + k8] = pk;
    }
    for (int i = tid; i < 512; i += 256) {
        int r = i >> 4, k8 = (i & 15) * 8;
        uint4 v = *(const uint4*)&mid[(size_t)(rb + r) * NE + k8];
        *(uint4*)&am[r * 136 + k8] = v;
    }
    __syncthreads();
    const int wave = tid >> 6, lane = tid & 63;
    const int quad = lane >> 4, l15 = lane & 15;
    const int mt = wave & 1, nh = wave >> 1;
    half8 af[4];
#pragma unroll
    for (int kt = 0; kt < 4; kt++)
        af[kt] = *(const half8*)&am[(mt * 16 + l15) * 136 + kt * 32 + quad * 8];
#pragma unroll
    for (int nt = 0; nt < 4; nt++) {
        int n0 = (nh * 4 + nt) * 16;
        f32x4 acc = {0.f, 0.f, 0.f, 0.f};
#pragma unroll
        for (int kt = 0; kt < 4; kt++) {
            half8 bf = *(const half8*)&wf[(n0 + l15) * 136 + kt * 32 + quad * 8];
            acc = __builtin_amdgcn_mfma_f32_16x16x32_f16(af[kt], bf, acc, 0, 0, 0);
        }
#pragma unroll
        for (int r = 0; r < 4; r++)
            out[(size_t)(rb + mt * 16 + quad * 4 + r) * NE + n0 + l15] = acc[r];
    }
}

extern "C" void kernel_launch(void* const* d_in, const int* in_sizes, int n_in,
                              void* d_out, int out_size, void* d_ws, size_t ws_size,
                              hipStream_t stream) {
    const float* x     = (const float*)d_in[0];
    const float* theta = (const float*)d_in[1];
    const float* w_out = (const float*)d_in[2];
    const int*   mask  = (const int*)d_in[3];
    float* out = (float*)d_out;

    const size_t opart_elems = (size_t)2 * 64 * NS * ND;   // 8.39 MB
    const size_t lpart_elems = (size_t)2 * 64 * NS;        // 1.05 MB
    const size_t need = (opart_elems + lpart_elems) * sizeof(float);

    if (ws_size >= need) {
        float* Opart = (float*)d_ws;
        float* lpart = Opart + opart_elems;
        attn_partial<<<dim3(NB * NH * 4, 2), 512, 0, stream>>>(x, theta, mask, Opart, lpart);
        proj_combine<<<NB * NS / 32, 256, 0, stream>>>(Opart, lpart, w_out, out);
    } else {
        unsigned short* mid16 = (unsigned short*)d_ws;     // 2 MB
        attn_full<<<NB * NH * 8, 512, 0, stream>>>(x, theta, mask, mid16);
        proj_mid<<<NB * NS / 32, 256, 0, stream>>>(mid16, w_out, out);
    }
}